// Round 1
// baseline (4013.158 us; speedup 1.0000x reference)
//
#include <hip/hip_runtime.h>

#define BS   16
#define NMEM 256
#define NQ   63
#define T    64          // NQ + 1
#define D    512
#define H    512
#define G4   2048        // 4*H

#define K2C  2.885390081777927f   // 2*log2(e)

// ---------------- workspace layout (float offsets) ----------------
enum : size_t {
    OFF_XW = 0,                          // [T][BS][G4]
    OFF_YS = OFF_XW + (size_t)T*BS*G4,   // [T+1][BS][H]
    OFF_C  = OFF_YS + (size_t)(T+1)*BS*H,// [BS][H]
    OFF_AF = OFF_C  + (size_t)BS*H,      // [BS][NMEM][H]
    OFF_Q  = OFF_AF + (size_t)BS*NMEM*H, // [T][BS][H]
    OFF_X  = OFF_Q  + (size_t)T*BS*H,    // [T][BS][D]
    OFF_B  = OFF_X  + (size_t)T*BS*D,    // [G4]
};

// ---------------- prep: build x, bias, h0, c0 ----------------
__global__ void prep(const float* __restrict__ lstm_in, const float* __restrict__ init_h,
                     const float* __restrict__ init_c, const float* __restrict__ init_i,
                     const float* __restrict__ b_ih, const float* __restrict__ b_hh,
                     float* __restrict__ xbuf, float* __restrict__ biasbuf,
                     float* __restrict__ ys0, float* __restrict__ cbuf)
{
    int i = blockIdx.x * blockDim.x + threadIdx.x;
    const int NX = T*BS*D;
    if (i < NX) {
        int d = i & 511; int r = i >> 9; int t = r >> 4; int b = r & 15;
        xbuf[i] = (t == 0) ? init_i[d] : lstm_in[((size_t)(b*NQ) + (t-1))*D + d];
    } else if (i < NX + G4) {
        int j = i - NX; biasbuf[j] = b_ih[j] + b_hh[j];
    } else if (i < NX + G4 + BS*H) {
        int j = i - (NX + G4); ys0[j] = init_h[j & 511];
    } else if (i < NX + G4 + 2*BS*H) {
        int j = i - (NX + G4 + BS*H); cbuf[j] = init_c[j & 511];
    }
}

// ---------------- fp32 GEMM: C[M,N] = A[M,K] * op(B) (+bias[n]) ----------------
// BT=true : B is [N,K] row-major (C = A * B^T)
// BT=false: B is [K,N] row-major (C = A * B)
// tiles 64x64, K-tile 16, 256 threads, 4x4 accum per thread
template<bool BT>
__global__ __launch_bounds__(256) void gemm64(const float* __restrict__ A,
                                              const float* __restrict__ B,
                                              float* __restrict__ C,
                                              const float* __restrict__ bias,
                                              int M, int N, int K)
{
    __shared__ float As[16][68];
    __shared__ float Bs[16][68];
    const int tid = threadIdx.x;
    const int tx = tid & 15, ty = tid >> 4;
    const int tm = blockIdx.y * 64, tn = blockIdx.x * 64;
    const int lr = tid >> 2, lk = (tid & 3) << 2;
    float acc[4][4] = {};
    for (int k0 = 0; k0 < K; k0 += 16) {
        float4 a4 = *(const float4*)(A + (size_t)(tm + lr) * K + k0 + lk);
        As[lk+0][lr] = a4.x; As[lk+1][lr] = a4.y; As[lk+2][lr] = a4.z; As[lk+3][lr] = a4.w;
        if (BT) {
            float4 b4 = *(const float4*)(B + (size_t)(tn + lr) * K + k0 + lk);
            Bs[lk+0][lr] = b4.x; Bs[lk+1][lr] = b4.y; Bs[lk+2][lr] = b4.z; Bs[lk+3][lr] = b4.w;
        } else {
            const int kr = tid >> 4, n4 = (tid & 15) << 2;
            float4 b4 = *(const float4*)(B + (size_t)(k0 + kr) * N + tn + n4);
            *(float4*)&Bs[kr][n4] = b4;
        }
        __syncthreads();
#pragma unroll
        for (int kk = 0; kk < 16; ++kk) {
            float4 av = *(const float4*)&As[kk][ty << 2];
            float4 bv = *(const float4*)&Bs[kk][tx << 2];
            const float* ap = (const float*)&av;
            const float* bp = (const float*)&bv;
#pragma unroll
            for (int i = 0; i < 4; ++i) {
                acc[i][0] += ap[i] * bp[0];
                acc[i][1] += ap[i] * bp[1];
                acc[i][2] += ap[i] * bp[2];
                acc[i][3] += ap[i] * bp[3];
            }
        }
        __syncthreads();
    }
#pragma unroll
    for (int i = 0; i < 4; ++i) {
        int row = tm + (ty << 2) + i;
        float4 o;
        o.x = acc[i][0]; o.y = acc[i][1]; o.z = acc[i][2]; o.w = acc[i][3];
        if (bias) {
            o.x += bias[tn + (tx<<2) + 0]; o.y += bias[tn + (tx<<2) + 1];
            o.z += bias[tn + (tx<<2) + 2]; o.w += bias[tn + (tx<<2) + 3];
        }
        *(float4*)(C + (size_t)row * N + tn + (tx << 2)) = o;
    }
}

// ---------------- one LSTM step ----------------
// grid 32 blocks x 1024 thr. wave = one batch b; lane = (g,jl) -> one row dot.
__global__ __launch_bounds__(1024) void lstm_step(const float* __restrict__ xWt,
                                                  const float* __restrict__ w_hh,
                                                  const float* __restrict__ h_prev,
                                                  float* __restrict__ cbuf,
                                                  float* __restrict__ h_out)
{
    __shared__ float hs[16][516];
    __shared__ float gl[4][16][17];
    const int tid = threadIdx.x;
    for (int i = tid; i < BS*H/4; i += 1024) {
        float4 vv = ((const float4*)h_prev)[i];
        int e = i << 2; int bb = e >> 9; int hh = e & 511;
        *(float4*)&hs[bb][hh] = vv;
    }
    __syncthreads();
    const int b    = tid >> 6;        // wave index = batch
    const int lane = tid & 63;
    const int jl = lane & 15, g = lane >> 4;
    const int jglob = blockIdx.x * 16 + jl;
    const int row   = g * H + jglob;
    const float4* wrow = (const float4*)(w_hh + (size_t)row * H);
    const float4* hb   = (const float4*)&hs[b][0];
    float acc = 0.f;
#pragma unroll 8
    for (int k = 0; k < H/4; ++k) {
        float4 w4 = wrow[k], h4 = hb[k];
        acc += w4.x*h4.x; acc += w4.y*h4.y; acc += w4.z*h4.z; acc += w4.w*h4.w;
    }
    gl[g][jl][b] = acc + xWt[b * G4 + row];
    __syncthreads();
    if (tid < 256) {
        const int b2 = tid & 15, jl2 = tid >> 4;
        const int j2 = blockIdx.x * 16 + jl2;
        float iv = gl[0][jl2][b2], fv = gl[1][jl2][b2];
        float gv = gl[2][jl2][b2], ov = gl[3][jl2][b2];
        int idx = b2 * H + j2;
        float c_old = cbuf[idx];
        float si = 1.f / (1.f + __expf(-iv));
        float sf = 1.f / (1.f + __expf(-fv));
        float so = 1.f / (1.f + __expf(-ov));
        float cn = sf * c_old + si * tanhf(gv);
        float hn = so * tanhf(cn);
        cbuf[idx]  = cn;
        h_out[idx] = hn;
    }
}

// ---------------- fused attention: score[b,t,m] = sum_h tanh(af+q)*v ----------------
// grid (mc=4, tc=4, b=16), 256 thr. thread = (m lane 0..63, tg 0..3) owning 4 t's.
__global__ __launch_bounds__(256) void attn(const float* __restrict__ af,
                                            const float* __restrict__ q,
                                            const float* __restrict__ v,
                                            float* __restrict__ out)
{
    __shared__ float afs[64][68];
    __shared__ float qs[16][516];
    __shared__ float vs[512];
    const int tid = threadIdx.x;
    const int mc = blockIdx.x, tc = blockIdx.y, b = blockIdx.z;
    // stage q rows (scaled by 2*log2e)
    for (int i = tid; i < 16*128; i += 256) {
        int t = i >> 7, h4 = (i & 127) << 2;
        float4 x = *(const float4*)(q + ((size_t)((tc*16 + t)*16 + b) << 9) + h4);
        x.x *= K2C; x.y *= K2C; x.z *= K2C; x.w *= K2C;
        *(float4*)&qs[t][h4] = x;
    }
    for (int i = tid; i < 128; i += 256)
        *(float4*)&vs[i << 2] = *(const float4*)(v + (i << 2));
    const int ml = tid & 63, tg = tid >> 6;
    float acc[4] = {0.f, 0.f, 0.f, 0.f};
    for (int hc = 0; hc < 8; ++hc) {
        __syncthreads();   // afs reuse hazard (also covers qs/vs on first iter)
        for (int i = tid; i < 64*16; i += 256) {
            int m = i >> 4, h4 = (i & 15) << 2;
            float4 x = *(const float4*)(af + ((size_t)(b*NMEM + mc*64 + m) << 9) + hc*64 + h4);
            x.x *= K2C; x.y *= K2C; x.z *= K2C; x.w *= K2C;
            *(float4*)&afs[m][h4] = x;
        }
        __syncthreads();
#pragma unroll
        for (int h8 = 0; h8 < 8; ++h8) {
            float4 a0 = *(const float4*)&afs[ml][h8*8 + 0];
            float4 a1 = *(const float4*)&afs[ml][h8*8 + 4];
            float4 v0 = *(const float4*)&vs[hc*64 + h8*8 + 0];
            float4 v1 = *(const float4*)&vs[hc*64 + h8*8 + 4];
            const float* ap = (const float*)&a0;  // a0,a1 contiguous in regs? keep separate:
            const float* vp = (const float*)&v0;
#pragma unroll
            for (int tt = 0; tt < 4; ++tt) {
                int t = tg*4 + tt;
                float4 q0 = *(const float4*)&qs[t][hc*64 + h8*8 + 0];
                float4 q1 = *(const float4*)&qs[t][hc*64 + h8*8 + 4];
                const float* qp0 = (const float*)&q0;
                const float* qp1 = (const float*)&q1;
                float s = acc[tt];
#pragma unroll
                for (int j = 0; j < 4; ++j) {
                    float arg = ap[j] + qp0[j];
                    float e = exp2f(arg);
                    float r = __builtin_amdgcn_rcpf(e + 1.f);
                    s = fmaf(vp[j], r, s);
                }
                const float* ap1 = (const float*)&a1;
                const float* vp1 = (const float*)&v1;
#pragma unroll
                for (int j = 0; j < 4; ++j) {
                    float arg = ap1[j] + qp1[j];
                    float e = exp2f(arg);
                    float r = __builtin_amdgcn_rcpf(e + 1.f);
                    s = fmaf(vp1[j], r, s);
                }
                acc[tt] = s;
            }
        }
    }
    // Sv = sum of v over all 512 h
    float Sv = 0.f;
    for (int i = 0; i < 512; i += 4) {
        float4 t4 = *(const float4*)&vs[i];
        Sv += t4.x + t4.y + t4.z + t4.w;
    }
#pragma unroll
    for (int tt = 0; tt < 4; ++tt) {
        int t = tc*16 + tg*4 + tt;
        out[((size_t)b*T + t)*NMEM + mc*64 + ml] = Sv - 2.f*acc[tt];
    }
}

extern "C" void kernel_launch(void* const* d_in, const int* in_sizes, int n_in,
                              void* d_out, int out_size, void* d_ws, size_t ws_size,
                              hipStream_t stream)
{
    const float* ks      = (const float*)d_in[0];
    const float* lstm_in = (const float*)d_in[2];
    const float* init_h  = (const float*)d_in[3];
    const float* init_c  = (const float*)d_in[4];
    const float* init_i  = (const float*)d_in[5];
    const float* w_ih    = (const float*)d_in[6];
    const float* w_hh    = (const float*)d_in[7];
    const float* b_ih    = (const float*)d_in[8];
    const float* b_hh    = (const float*)d_in[9];
    const float* wm      = (const float*)d_in[10];
    const float* wq      = (const float*)d_in[11];
    const float* av      = (const float*)d_in[12];

    float* ws   = (float*)d_ws;
    float* xW   = ws + OFF_XW;
    float* ys   = ws + OFF_YS;
    float* cbuf = ws + OFF_C;
    float* af   = ws + OFF_AF;
    float* qb   = ws + OFF_Q;
    float* xb   = ws + OFF_X;
    float* bias = ws + OFF_B;

    const int prep_n = T*BS*D + G4 + 2*BS*H;           // 542720
    prep<<<(prep_n + 255)/256, 256, 0, stream>>>(lstm_in, init_h, init_c, init_i,
                                                 b_ih, b_hh, xb, bias, ys, cbuf);
    // af[4096,512] = ks @ wm           (B is [K,N])
    gemm64<false><<<dim3(8, 64), 256, 0, stream>>>(ks, wm, af, nullptr, BS*NMEM, H, D);
    // xW[1024,2048] = x @ w_ih^T + b   (B is [N,K])
    gemm64<true><<<dim3(32, 16), 256, 0, stream>>>(xb, w_ih, xW, bias, T*BS, G4, D);
    for (int t = 0; t < T; ++t) {
        lstm_step<<<32, 1024, 0, stream>>>(xW + (size_t)t*BS*G4, w_hh,
                                           ys + (size_t)t*BS*H, cbuf,
                                           ys + (size_t)(t+1)*BS*H);
    }
    // qb[1024,512] = ys[1..64] @ wq    (B is [K,N])
    gemm64<false><<<dim3(8, 16), 256, 0, stream>>>(ys + BS*H, wq, qb, nullptr, T*BS, H, H);
    attn<<<dim3(4, 4, 16), 256, 0, stream>>>(af, qb, av, (float*)d_out);
}

// Round 2
// 1037.632 us; speedup vs baseline: 3.8676x; 3.8676x over previous
//
#include <hip/hip_runtime.h>

#define BS   16
#define NMEM 256
#define NQ   63
#define T    64          // NQ + 1
#define D    512
#define H    512
#define G4   2048        // 4*H

#define K2C  2.885390081777927f   // 2*log2(e)

// ---------------- workspace layout (float offsets) ----------------
enum : size_t {
    OFF_XW  = 0,                            // [T][BS][G4]
    OFF_YS  = OFF_XW  + (size_t)T*BS*G4,    // [T+1][BS][H]  (b-major, for q-gemm)
    OFF_YST = OFF_YS  + (size_t)(T+1)*BS*H, // [T+1][H][BS]  (k-major, for recurrence)
    OFF_AF  = OFF_YST + (size_t)(T+1)*BS*H, // [BS][NMEM][H]
    OFF_Q   = OFF_AF  + (size_t)BS*NMEM*H,  // [T][BS][H]
    OFF_X   = OFF_Q   + (size_t)T*BS*H,     // [T][BS][D]
    OFF_B   = OFF_X   + (size_t)T*BS*D,     // [G4]
    OFF_BAR = OFF_B   + (size_t)G4,         // 256 ints (16 shards, stride 16)
};

// ---------------- prep: build x, bias, ysT[0] ----------------
__global__ void prep(const float* __restrict__ lstm_in, const float* __restrict__ init_h,
                     const float* __restrict__ init_i,
                     const float* __restrict__ b_ih, const float* __restrict__ b_hh,
                     float* __restrict__ xbuf, float* __restrict__ biasbuf,
                     float* __restrict__ ysT0)
{
    int i = blockIdx.x * blockDim.x + threadIdx.x;
    const int NX = T*BS*D;
    if (i < NX) {
        int d = i & 511; int r = i >> 9; int t = r >> 4; int b = r & 15;
        xbuf[i] = (t == 0) ? init_i[d] : lstm_in[((size_t)(b*NQ) + (t-1))*D + d];
    } else if (i < NX + G4) {
        int j = i - NX; biasbuf[j] = b_ih[j] + b_hh[j];
    } else if (i < NX + G4 + BS*H) {
        int j = i - (NX + G4);               // j = k*16 + b
        ysT0[j] = init_h[j >> 4];
    }
}

// ---------------- fp32 GEMM: C[M,N] = A[M,K] * op(B) (+bias[n]) ----------------
template<bool BT>
__global__ __launch_bounds__(256) void gemm64(const float* __restrict__ A,
                                              const float* __restrict__ B,
                                              float* __restrict__ C,
                                              const float* __restrict__ bias,
                                              int M, int N, int K)
{
    __shared__ float As[16][68];
    __shared__ float Bs[16][68];
    const int tid = threadIdx.x;
    const int tx = tid & 15, ty = tid >> 4;
    const int tm = blockIdx.y * 64, tn = blockIdx.x * 64;
    const int lr = tid >> 2, lk = (tid & 3) << 2;
    float acc[4][4] = {};
    for (int k0 = 0; k0 < K; k0 += 16) {
        float4 a4 = *(const float4*)(A + (size_t)(tm + lr) * K + k0 + lk);
        As[lk+0][lr] = a4.x; As[lk+1][lr] = a4.y; As[lk+2][lr] = a4.z; As[lk+3][lr] = a4.w;
        if (BT) {
            float4 b4 = *(const float4*)(B + (size_t)(tn + lr) * K + k0 + lk);
            Bs[lk+0][lr] = b4.x; Bs[lk+1][lr] = b4.y; Bs[lk+2][lr] = b4.z; Bs[lk+3][lr] = b4.w;
        } else {
            const int kr = tid >> 4, n4 = (tid & 15) << 2;
            float4 b4 = *(const float4*)(B + (size_t)(k0 + kr) * N + tn + n4);
            *(float4*)&Bs[kr][n4] = b4;
        }
        __syncthreads();
#pragma unroll
        for (int kk = 0; kk < 16; ++kk) {
            float4 av = *(const float4*)&As[kk][ty << 2];
            float4 bv = *(const float4*)&Bs[kk][tx << 2];
            const float* ap = (const float*)&av;
            const float* bp = (const float*)&bv;
#pragma unroll
            for (int i = 0; i < 4; ++i) {
                acc[i][0] += ap[i] * bp[0];
                acc[i][1] += ap[i] * bp[1];
                acc[i][2] += ap[i] * bp[2];
                acc[i][3] += ap[i] * bp[3];
            }
        }
        __syncthreads();
    }
#pragma unroll
    for (int i = 0; i < 4; ++i) {
        int row = tm + (ty << 2) + i;
        float4 o;
        o.x = acc[i][0]; o.y = acc[i][1]; o.z = acc[i][2]; o.w = acc[i][3];
        if (bias) {
            o.x += bias[tn + (tx<<2) + 0]; o.y += bias[tn + (tx<<2) + 1];
            o.z += bias[tn + (tx<<2) + 2]; o.w += bias[tn + (tx<<2) + 3];
        }
        *(float4*)(C + (size_t)row * N + tn + (tx << 2)) = o;
    }
}

// ---------------- persistent LSTM: all 64 steps, weights in VGPRs ----------------
// 256 blocks x 512 thr. Block owns j-slice of 2 (x 4 gates). Lane = (b 16, gate 4).
// Wave = k-chunk of 64. Weights: 128 VGPRs/thread, loaded once, reused 64 steps.
// h exchanged via ysT[t][k][b] with agent-scope atomics; 16-shard phase barrier.
__global__ __launch_bounds__(512, 2) void lstm_all(
    const float* __restrict__ xW,     // [T][BS][G4]
    const float* __restrict__ w_hh,   // [G4][H]
    const float* __restrict__ init_c, // [H]
    float* __restrict__ ys,           // [T+1][BS][H]; [0] unused
    float* __restrict__ ysT,          // [T+1][H][BS]; [0] pre-filled by prep
    int* __restrict__ bar)            // 16 shards, stride 16 ints
{
    const int tid  = threadIdx.x;
    const int blk  = blockIdx.x;          // 0..255
    const int j0   = blk * 2;
    const int lane = tid & 63;
    const int b    = lane & 15;
    const int g    = lane >> 4;           // gate 0..3 (i,f,g,o)
    const int kh   = tid >> 6;            // 0..7
    const int k0   = kh * 64;
    const int row0 = g*512 + j0;          // jj = 0
    const int row1 = row0 + 1;            // jj = 1

    // ---- one-time weight preload into VGPRs ----
    float w0[64], w1[64];
    {
        const float4* p0 = (const float4*)(w_hh + (size_t)row0*H + k0);
        const float4* p1 = (const float4*)(w_hh + (size_t)row1*H + k0);
#pragma unroll
        for (int i = 0; i < 16; ++i) {
            float4 a = p0[i];
            w0[4*i+0]=a.x; w0[4*i+1]=a.y; w0[4*i+2]=a.z; w0[4*i+3]=a.w;
        }
#pragma unroll
        for (int i = 0; i < 16; ++i) {
            float4 a = p1[i];
            w1[4*i+0]=a.x; w1[4*i+1]=a.y; w1[4*i+2]=a.z; w1[4*i+3]=a.w;
        }
    }
    __shared__ float part[8][4][2][16];   // [kh][gate][jj][b]
    __shared__ float cst[2][16];          // [jj][b]
    if (tid < 32) cst[tid>>4][tid&15] = init_c[j0 + (tid>>4)];
    __syncthreads();

    const int myshard = blk & 15;
    for (int t = 0; t < T; ++t) {
        // ---- load vh = h_t[k0..k0+63] for my b (64B line per load instr) ----
        const float* hsrc = ysT + (size_t)t*BS*H + k0*16 + b;
        float vh[64];
#pragma unroll
        for (int i = 0; i < 64; ++i)
            vh[i] = __hip_atomic_load(hsrc + i*16, __ATOMIC_RELAXED, __HIP_MEMORY_SCOPE_AGENT);
        // ---- pure-VGPR dot-product partials ----
        float a0 = 0.f, a1 = 0.f;
#pragma unroll
        for (int i = 0; i < 64; ++i) {
            a0 = fmaf(w0[i], vh[i], a0);
            a1 = fmaf(w1[i], vh[i], a1);
        }
        part[kh][g][0][b] = a0;
        part[kh][g][1][b] = a1;
        __syncthreads();
        // ---- finalize: 32 threads = (b, jj) ----
        if (tid < 32) {
            const int b2 = tid & 15, jj = tid >> 4;
            float gi=0.f, gf=0.f, gg=0.f, go=0.f;
#pragma unroll
            for (int k = 0; k < 8; ++k) {
                gi += part[k][0][jj][b2];
                gf += part[k][1][jj][b2];
                gg += part[k][2][jj][b2];
                go += part[k][3][jj][b2];
            }
            const float* xwp = xW + (size_t)t*BS*G4 + b2*G4 + (j0 + jj);
            gi += xwp[0]; gf += xwp[512]; gg += xwp[1024]; go += xwp[1536];
            float si = 1.f/(1.f+__expf(-gi));
            float sf = 1.f/(1.f+__expf(-gf));
            float so = 1.f/(1.f+__expf(-go));
            float cn = sf*cst[jj][b2] + si*tanhf(gg);
            float hn = so*tanhf(cn);
            cst[jj][b2] = cn;
            // coherent store for the recurrence (k-major)
            __hip_atomic_store(ysT + (size_t)(t+1)*BS*H + (j0+jj)*16 + b2, hn,
                               __ATOMIC_RELAXED, __HIP_MEMORY_SCOPE_AGENT);
            // plain store for the q-gemm (b-major); visible at kernel end
            ys[(size_t)(t+1)*BS*H + b2*H + j0 + jj] = hn;
        }
        __syncthreads();   // compiler drains vmcnt before s_barrier -> stores complete
        if (tid == 0)
            __hip_atomic_fetch_add(&bar[myshard*16], 1, __ATOMIC_RELEASE, __HIP_MEMORY_SCOPE_AGENT);
        if (tid < 16) {
            const int tgt = 16*(t+1);
            while (__hip_atomic_load(&bar[tid*16], __ATOMIC_ACQUIRE, __HIP_MEMORY_SCOPE_AGENT) < tgt)
                __builtin_amdgcn_s_sleep(1);
        }
        __syncthreads();
    }
}

// ---------------- fused attention: score[b,t,m] = sum_h tanh(af+q)*v ----------------
// grid (mc=4, tc=16, b=16) = 1024 blocks, 256 thr. thread = (m lane 0..63, tg -> one t).
__global__ __launch_bounds__(256) void attn(const float* __restrict__ af,
                                            const float* __restrict__ q,
                                            const float* __restrict__ v,
                                            float* __restrict__ out)
{
    __shared__ float afs[64][68];
    __shared__ float qs[4][516];
    __shared__ float vs[512];
    const int tid = threadIdx.x;
    const int mc = blockIdx.x, tc = blockIdx.y, b = blockIdx.z;
    for (int i = tid; i < 4*128; i += 256) {
        int t = i >> 7, h4 = (i & 127) << 2;
        float4 x = *(const float4*)(q + ((size_t)((tc*4 + t)*16 + b) << 9) + h4);
        x.x *= K2C; x.y *= K2C; x.z *= K2C; x.w *= K2C;
        *(float4*)&qs[t][h4] = x;
    }
    for (int i = tid; i < 128; i += 256)
        *(float4*)&vs[i << 2] = *(const float4*)(v + (i << 2));
    const int ml = tid & 63, tg = tid >> 6;
    float acc = 0.f;
    for (int hc = 0; hc < 8; ++hc) {
        __syncthreads();   // afs reuse hazard (also covers qs/vs on first iter)
        for (int i = tid; i < 64*16; i += 256) {
            int m = i >> 4, h4 = (i & 15) << 2;
            float4 x = *(const float4*)(af + ((size_t)(b*NMEM + mc*64 + m) << 9) + hc*64 + h4);
            x.x *= K2C; x.y *= K2C; x.z *= K2C; x.w *= K2C;
            *(float4*)&afs[m][h4] = x;
        }
        __syncthreads();
#pragma unroll
        for (int h8 = 0; h8 < 8; ++h8) {
            float4 a0 = *(const float4*)&afs[ml][h8*8 + 0];
            float4 a1 = *(const float4*)&afs[ml][h8*8 + 4];
            float4 v0 = *(const float4*)&vs[hc*64 + h8*8 + 0];
            float4 v1 = *(const float4*)&vs[hc*64 + h8*8 + 4];
            float4 q0 = *(const float4*)&qs[tg][hc*64 + h8*8 + 0];
            float4 q1 = *(const float4*)&qs[tg][hc*64 + h8*8 + 4];
            const float* ap0 = (const float*)&a0; const float* ap1 = (const float*)&a1;
            const float* vp0 = (const float*)&v0; const float* vp1 = (const float*)&v1;
            const float* qp0 = (const float*)&q0; const float* qp1 = (const float*)&q1;
            float s = acc;
#pragma unroll
            for (int j = 0; j < 4; ++j) {
                float e = exp2f(ap0[j] + qp0[j]);
                s = fmaf(vp0[j], __builtin_amdgcn_rcpf(e + 1.f), s);
            }
#pragma unroll
            for (int j = 0; j < 4; ++j) {
                float e = exp2f(ap1[j] + qp1[j]);
                s = fmaf(vp1[j], __builtin_amdgcn_rcpf(e + 1.f), s);
            }
            acc = s;
        }
    }
    float Sv = 0.f;
    for (int i = 0; i < 512; i += 4) {
        float4 t4 = *(const float4*)&vs[i];
        Sv += t4.x + t4.y + t4.z + t4.w;
    }
    out[((size_t)b*T + tc*4 + tg)*NMEM + mc*64 + ml] = Sv - 2.f*acc;
}

extern "C" void kernel_launch(void* const* d_in, const int* in_sizes, int n_in,
                              void* d_out, int out_size, void* d_ws, size_t ws_size,
                              hipStream_t stream)
{
    const float* ks      = (const float*)d_in[0];
    const float* lstm_in = (const float*)d_in[2];
    const float* init_h  = (const float*)d_in[3];
    const float* init_c  = (const float*)d_in[4];
    const float* init_i  = (const float*)d_in[5];
    const float* w_ih    = (const float*)d_in[6];
    const float* w_hh    = (const float*)d_in[7];
    const float* b_ih    = (const float*)d_in[8];
    const float* b_hh    = (const float*)d_in[9];
    const float* wm      = (const float*)d_in[10];
    const float* wq      = (const float*)d_in[11];
    const float* av      = (const float*)d_in[12];

    float* ws   = (float*)d_ws;
    float* xW   = ws + OFF_XW;
    float* ys   = ws + OFF_YS;
    float* ysT  = ws + OFF_YST;
    float* af   = ws + OFF_AF;
    float* qb   = ws + OFF_Q;
    float* xb   = ws + OFF_X;
    float* bias = ws + OFF_B;
    int*   bar  = (int*)(ws + OFF_BAR);

    hipMemsetAsync(bar, 0, 256*sizeof(int), stream);

    const int prep_n = T*BS*D + G4 + BS*H;
    prep<<<(prep_n + 255)/256, 256, 0, stream>>>(lstm_in, init_h, init_i,
                                                 b_ih, b_hh, xb, bias, ysT);
    // af[4096,512] = ks @ wm
    gemm64<false><<<dim3(8, 64), 256, 0, stream>>>(ks, wm, af, nullptr, BS*NMEM, H, D);
    // xW[1024,2048] = x @ w_ih^T + b
    gemm64<true><<<dim3(32, 16), 256, 0, stream>>>(xb, w_ih, xW, bias, T*BS, G4, D);
    // all 64 LSTM steps in one persistent kernel
    lstm_all<<<256, 512, 0, stream>>>(xW, w_hh, init_c, ys, ysT, bar);
    // qb[1024,512] = ys[1..64] @ wq
    gemm64<false><<<dim3(8, 16), 256, 0, stream>>>(ys + BS*H, wq, qb, nullptr, T*BS, H, H);
    attn<<<dim3(4, 16, 16), 256, 0, stream>>>(af, qb, av, (float*)d_out);
}

// Round 3
// 534.379 us; speedup vs baseline: 7.5099x; 1.9418x over previous
//
#include <hip/hip_runtime.h>

#define BS   16
#define NMEM 256
#define NQ   63
#define T    64          // NQ + 1
#define D    512
#define H    512
#define G4   2048        // 4*H

#define K2C  2.885390081777927f   // 2*log2(e)

typedef __attribute__((ext_vector_type(8))) short short8;
typedef __attribute__((ext_vector_type(4))) float float4v;

// ---------------- workspace layout (float offsets) ----------------
enum : size_t {
    OFF_XW  = 0,                            // [T][BS][G4]
    OFF_YS  = OFF_XW  + (size_t)T*BS*G4,    // [T+1][BS][H]  (fp32, b-major, for q-gemm)
    OFF_HB  = OFF_YS  + (size_t)(T+1)*BS*H, // [T+1][2][8192] bf16 hi/lo  == (T+1)*8192 floats
    OFF_AF  = OFF_HB  + (size_t)(T+1)*BS*H, // [BS][NMEM][H]
    OFF_Q   = OFF_AF  + (size_t)BS*NMEM*H,  // [T][BS][H]
    OFF_X   = OFF_Q   + (size_t)T*BS*H,     // [T][BS][D]
    OFF_B   = OFF_X   + (size_t)T*BS*D,     // [G4]
    OFF_BAR = OFF_B   + (size_t)G4,         // 1 int
};

__device__ inline unsigned short bf16_rn(float x) {
    union { float f; unsigned u; } a; a.f = x;
    unsigned r = a.u + 0x7FFFu + ((a.u >> 16) & 1u);
    return (unsigned short)(r >> 16);
}
__device__ inline float bf16_to_f(unsigned short s) {
    union { float f; unsigned u; } a; a.u = ((unsigned)s) << 16;
    return a.f;
}

// ---------------- prep: build x, bias, hbuf[0] ----------------
// hbuf element layout (per t): hi[8192], lo[8192]; index e = ((k>>3)*16 + b)*8 + (k&7)
__global__ void prep(const float* __restrict__ lstm_in, const float* __restrict__ init_h,
                     const float* __restrict__ init_i,
                     const float* __restrict__ b_ih, const float* __restrict__ b_hh,
                     float* __restrict__ xbuf, float* __restrict__ biasbuf,
                     unsigned short* __restrict__ hb0)
{
    int i = blockIdx.x * blockDim.x + threadIdx.x;
    const int NX = T*BS*D;
    if (i < NX) {
        int d = i & 511; int r = i >> 9; int t = r >> 4; int b = r & 15;
        xbuf[i] = (t == 0) ? init_i[d] : lstm_in[((size_t)(b*NQ) + (t-1))*D + d];
    } else if (i < NX + G4) {
        int j = i - NX; biasbuf[j] = b_ih[j] + b_hh[j];
    } else if (i < NX + G4 + 8192) {
        int e = i - (NX + G4);
        int chunk = e >> 3, iw = e & 7;
        int k = (chunk >> 4) * 8 + iw;       // b = chunk & 15 (unused: init_h same for all b)
        float h0 = init_h[k];
        unsigned short hi = bf16_rn(h0);
        unsigned short lo = bf16_rn(h0 - bf16_to_f(hi));
        hb0[e] = hi;
        hb0[8192 + e] = lo;
    }
}

// ---------------- fp32 GEMM: C[M,N] = A[M,K] * op(B) (+bias[n]) ----------------
template<bool BT>
__global__ __launch_bounds__(256) void gemm64(const float* __restrict__ A,
                                              const float* __restrict__ B,
                                              float* __restrict__ C,
                                              const float* __restrict__ bias,
                                              int M, int N, int K)
{
    __shared__ float As[16][68];
    __shared__ float Bs[16][68];
    const int tid = threadIdx.x;
    const int tx = tid & 15, ty = tid >> 4;
    const int tm = blockIdx.y * 64, tn = blockIdx.x * 64;
    const int lr = tid >> 2, lk = (tid & 3) << 2;
    float acc[4][4] = {};
    for (int k0 = 0; k0 < K; k0 += 16) {
        float4 a4 = *(const float4*)(A + (size_t)(tm + lr) * K + k0 + lk);
        As[lk+0][lr] = a4.x; As[lk+1][lr] = a4.y; As[lk+2][lr] = a4.z; As[lk+3][lr] = a4.w;
        if (BT) {
            float4 b4 = *(const float4*)(B + (size_t)(tn + lr) * K + k0 + lk);
            Bs[lk+0][lr] = b4.x; Bs[lk+1][lr] = b4.y; Bs[lk+2][lr] = b4.z; Bs[lk+3][lr] = b4.w;
        } else {
            const int kr = tid >> 4, n4 = (tid & 15) << 2;
            float4 b4 = *(const float4*)(B + (size_t)(k0 + kr) * N + tn + n4);
            *(float4*)&Bs[kr][n4] = b4;
        }
        __syncthreads();
#pragma unroll
        for (int kk = 0; kk < 16; ++kk) {
            float4 av = *(const float4*)&As[kk][ty << 2];
            float4 bv = *(const float4*)&Bs[kk][tx << 2];
            const float* ap = (const float*)&av;
            const float* bp = (const float*)&bv;
#pragma unroll
            for (int i = 0; i < 4; ++i) {
                acc[i][0] += ap[i] * bp[0];
                acc[i][1] += ap[i] * bp[1];
                acc[i][2] += ap[i] * bp[2];
                acc[i][3] += ap[i] * bp[3];
            }
        }
        __syncthreads();
    }
#pragma unroll
    for (int i = 0; i < 4; ++i) {
        int row = tm + (ty << 2) + i;
        float4 o;
        o.x = acc[i][0]; o.y = acc[i][1]; o.z = acc[i][2]; o.w = acc[i][3];
        if (bias) {
            o.x += bias[tn + (tx<<2) + 0]; o.y += bias[tn + (tx<<2) + 1];
            o.z += bias[tn + (tx<<2) + 2]; o.w += bias[tn + (tx<<2) + 3];
        }
        *(float4*)(C + (size_t)row * N + tn + (tx << 2)) = o;
    }
}

// ---------------- persistent LSTM, MFMA split-bf16, 32 blocks ----------------
// Block jt owns hidden j-tile of 16 (x 4 gates). 8 waves: w = 2*g + khalf.
// Wave holds B-frags of w_hh rows [g*512 + jt*16 .. +15], k in [khalf*256, +256)
// as bf16 hi+lo: 16 frags, zero lane redundancy. gates = h @ w_hh^T via
// D = A(h[16b x 32k]) * B(w^T[32k x 16j]); 3-term split-bf16 per k-tile.
__global__ __launch_bounds__(512, 2) void lstm_all(
    const float* __restrict__ xW,        // [T][BS][G4]
    const float* __restrict__ w_hh,      // [G4][H]
    const float* __restrict__ init_c,    // [H]
    float* __restrict__ ys,              // [T+1][BS][H]; [0] unused
    unsigned short* __restrict__ hbuf,   // [T+1][2][8192]; [0] from prep
    int* __restrict__ bar)
{
    const int tid   = threadIdx.x;
    const int jt    = blockIdx.x;        // 0..31 hidden j-tile
    const int w     = tid >> 6;          // wave 0..7
    const int g     = w >> 1;            // gate (i,f,g,o)
    const int khalf = w & 1;
    const int lane  = tid & 63;
    const int quad  = lane >> 4;
    const int l15   = lane & 15;

    // ---- one-time weight preload -> bf16 hi/lo fragments in VGPRs ----
    short8 bh[8], bl[8];
    {
        const int row = g*512 + jt*16 + l15;     // B n-index = lane&15
        const float* wr = w_hh + (size_t)row*H + khalf*256 + quad*8;
#pragma unroll
        for (int kt = 0; kt < 8; ++kt) {
            const float* wp = wr + kt*32;
#pragma unroll
            for (int i = 0; i < 8; ++i) {
                float v = wp[i];
                unsigned short hi = bf16_rn(v);
                bh[kt][i] = (short)hi;
                bl[kt][i] = (short)bf16_rn(v - bf16_to_f(hi));
            }
        }
    }

    __shared__ float part[8][64][4];     // [wave][lane][reg]
    __shared__ float cst[16][16];        // [b][j16] fp32 cell state (exact)
    const int b2 = tid >> 4, j16 = tid & 15;     // finalize mapping (tid<256)
    if (tid < 256) cst[b2][j16] = init_c[jt*16 + j16];

    // xW prefetch registers (step 0)
    float xwi=0.f, xwf=0.f, xwg=0.f, xwo=0.f;
    if (tid < 256) {
        const float* p = xW + (size_t)b2*G4 + jt*16 + j16;
        xwi = p[0]; xwf = p[512]; xwg = p[1024]; xwo = p[1536];
    }
    __syncthreads();

    for (int t = 0; t < T; ++t) {
        // ---- load h_t A-fragments (plain dwordx4; fresh via per-step inv) ----
        const short8* hhi = (const short8*)(hbuf + (size_t)t*16384);
        const short8* hlo = hhi + 1024;
        short8 ah[8], al[8];
#pragma unroll
        for (int kt = 0; kt < 8; ++kt) {
            int c = ((khalf*8 + kt)*4 + quad)*16 + l15;
            ah[kt] = hhi[c];
            al[kt] = hlo[c];
        }
        // ---- MFMA: two parallel chains, 3-term split-bf16 ----
        float4v acc0 = {0.f,0.f,0.f,0.f}, acc1 = {0.f,0.f,0.f,0.f};
#pragma unroll
        for (int kt = 0; kt < 8; ++kt) {
            acc0 = __builtin_amdgcn_mfma_f32_16x16x32_bf16(ah[kt], bh[kt], acc0, 0, 0, 0);
            acc1 = __builtin_amdgcn_mfma_f32_16x16x32_bf16(al[kt], bh[kt], acc1, 0, 0, 0);
            acc1 = __builtin_amdgcn_mfma_f32_16x16x32_bf16(ah[kt], bl[kt], acc1, 0, 0, 0);
        }
        acc0 += acc1;
        *(float4v*)&part[w][lane][0] = acc0;   // D: m(b)=quad*4+reg, n(j)=lane&15
        __syncthreads();

        // ---- finalize: 256 threads = (b2, j16) ----
        if (tid < 256) {
            const int lsrc = (b2 >> 2)*16 + j16, r = b2 & 3;
            float gi = part[0][lsrc][r] + part[1][lsrc][r] + xwi;
            float gf = part[2][lsrc][r] + part[3][lsrc][r] + xwf;
            float gg = part[4][lsrc][r] + part[5][lsrc][r] + xwg;
            float go = part[6][lsrc][r] + part[7][lsrc][r] + xwo;
            float si = 1.f/(1.f+__expf(-gi));
            float sf = 1.f/(1.f+__expf(-gf));
            float so = 1.f/(1.f+__expf(-go));
            float cn = sf*cst[b2][j16] + si*tanhf(gg);
            float hn = so*tanhf(cn);
            cst[b2][j16] = cn;
            ys[(size_t)(t+1)*BS*H + b2*H + jt*16 + j16] = hn;
            const int k = jt*16 + j16;
            const int e = ((k >> 3)*16 + b2)*8 + (k & 7);
            unsigned short hi = bf16_rn(hn);
            unsigned short* hb1 = hbuf + (size_t)(t+1)*16384;
            hb1[e]        = hi;
            hb1[8192 + e] = bf16_rn(hn - bf16_to_f(hi));
        }
        __syncthreads();   // all stores vmcnt-drained before any thread proceeds

        if (t < T-1) {
            // prefetch next step's xW under the barrier wait (static data, safe)
            if (tid < 256) {
                const float* p = xW + (size_t)(t+1)*BS*G4 + b2*G4 + jt*16 + j16;
                xwi = p[0]; xwf = p[512]; xwg = p[1024]; xwo = p[1536];
            }
            if (tid == 0) {
                // RELEASE RMW: waits stores, buffer_wbl2 -> h visible at L3
                __hip_atomic_fetch_add(bar, 1, __ATOMIC_RELEASE, __HIP_MEMORY_SCOPE_AGENT);
                const int tgt = 32*(t+1);
                while (__hip_atomic_load(bar, __ATOMIC_RELAXED, __HIP_MEMORY_SCOPE_AGENT) < tgt)
                    __builtin_amdgcn_s_sleep(1);
                // single invalidate per block per step; L1 is CU-wide, L2 XCD-wide
                __builtin_amdgcn_fence(__ATOMIC_ACQUIRE, "agent");
            }
            __syncthreads();
        }
    }
}

// ---------------- fused attention: score[b,t,m] = sum_h tanh(af+q)*v ----------------
__global__ __launch_bounds__(256) void attn(const float* __restrict__ af,
                                            const float* __restrict__ q,
                                            const float* __restrict__ v,
                                            float* __restrict__ out)
{
    __shared__ float afs[64][68];
    __shared__ float qs[4][516];
    __shared__ float vs[512];
    const int tid = threadIdx.x;
    const int mc = blockIdx.x, tc = blockIdx.y, b = blockIdx.z;
    for (int i = tid; i < 4*128; i += 256) {
        int t = i >> 7, h4 = (i & 127) << 2;
        float4 x = *(const float4*)(q + ((size_t)((tc*4 + t)*16 + b) << 9) + h4);
        x.x *= K2C; x.y *= K2C; x.z *= K2C; x.w *= K2C;
        *(float4*)&qs[t][h4] = x;
    }
    for (int i = tid; i < 128; i += 256)
        *(float4*)&vs[i << 2] = *(const float4*)(v + (i << 2));
    const int ml = tid & 63, tg = tid >> 6;
    float acc = 0.f;
    for (int hc = 0; hc < 8; ++hc) {
        __syncthreads();
        for (int i = tid; i < 64*16; i += 256) {
            int m = i >> 4, h4 = (i & 15) << 2;
            float4 x = *(const float4*)(af + ((size_t)(b*NMEM + mc*64 + m) << 9) + hc*64 + h4);
            x.x *= K2C; x.y *= K2C; x.z *= K2C; x.w *= K2C;
            *(float4*)&afs[m][h4] = x;
        }
        __syncthreads();
#pragma unroll
        for (int h8 = 0; h8 < 8; ++h8) {
            float4 a0 = *(const float4*)&afs[ml][h8*8 + 0];
            float4 a1 = *(const float4*)&afs[ml][h8*8 + 4];
            float4 v0 = *(const float4*)&vs[hc*64 + h8*8 + 0];
            float4 v1 = *(const float4*)&vs[hc*64 + h8*8 + 4];
            float4 q0 = *(const float4*)&qs[tg][hc*64 + h8*8 + 0];
            float4 q1 = *(const float4*)&qs[tg][hc*64 + h8*8 + 4];
            const float* ap0 = (const float*)&a0; const float* ap1 = (const float*)&a1;
            const float* vp0 = (const float*)&v0; const float* vp1 = (const float*)&v1;
            const float* qp0 = (const float*)&q0; const float* qp1 = (const float*)&q1;
            float s = acc;
#pragma unroll
            for (int j = 0; j < 4; ++j) {
                float e = exp2f(ap0[j] + qp0[j]);
                s = fmaf(vp0[j], __builtin_amdgcn_rcpf(e + 1.f), s);
            }
#pragma unroll
            for (int j = 0; j < 4; ++j) {
                float e = exp2f(ap1[j] + qp1[j]);
                s = fmaf(vp1[j], __builtin_amdgcn_rcpf(e + 1.f), s);
            }
            acc = s;
        }
    }
    float Sv = 0.f;
    for (int i = 0; i < 512; i += 4) {
        float4 t4 = *(const float4*)&vs[i];
        Sv += t4.x + t4.y + t4.z + t4.w;
    }
    out[((size_t)b*T + tc*4 + tg)*NMEM + mc*64 + ml] = Sv - 2.f*acc;
}

extern "C" void kernel_launch(void* const* d_in, const int* in_sizes, int n_in,
                              void* d_out, int out_size, void* d_ws, size_t ws_size,
                              hipStream_t stream)
{
    const float* ks      = (const float*)d_in[0];
    const float* lstm_in = (const float*)d_in[2];
    const float* init_h  = (const float*)d_in[3];
    const float* init_c  = (const float*)d_in[4];
    const float* init_i  = (const float*)d_in[5];
    const float* w_ih    = (const float*)d_in[6];
    const float* w_hh    = (const float*)d_in[7];
    const float* b_ih    = (const float*)d_in[8];
    const float* b_hh    = (const float*)d_in[9];
    const float* wm      = (const float*)d_in[10];
    const float* wq      = (const float*)d_in[11];
    const float* av      = (const float*)d_in[12];

    float* ws   = (float*)d_ws;
    float* xW   = ws + OFF_XW;
    float* ys   = ws + OFF_YS;
    unsigned short* hbuf = (unsigned short*)(ws + OFF_HB);
    float* af   = ws + OFF_AF;
    float* qb   = ws + OFF_Q;
    float* xb   = ws + OFF_X;
    float* bias = ws + OFF_B;
    int*   bar  = (int*)(ws + OFF_BAR);

    hipMemsetAsync(bar, 0, sizeof(int), stream);

    const int prep_n = T*BS*D + G4 + 8192;
    prep<<<(prep_n + 255)/256, 256, 0, stream>>>(lstm_in, init_h, init_i,
                                                 b_ih, b_hh, xb, bias, hbuf);
    // xW[1024,2048] = x @ w_ih^T + b
    gemm64<true><<<dim3(32, 16), 256, 0, stream>>>(xb, w_ih, xW, bias, T*BS, G4, D);
    // all 64 LSTM steps, one persistent kernel, 32 blocks
    lstm_all<<<32, 512, 0, stream>>>(xW, w_hh, init_c, ys, hbuf, bar);
    // af[4096,512] = ks @ wm
    gemm64<false><<<dim3(8, 64), 256, 0, stream>>>(ks, wm, af, nullptr, BS*NMEM, H, D);
    // qb[1024,512] = ys[1..64] @ wq
    gemm64<false><<<dim3(8, 16), 256, 0, stream>>>(ys + BS*H, wq, qb, nullptr, T*BS, H, H);
    attn<<<dim3(4, 16, 16), 256, 0, stream>>>(af, qb, av, (float*)d_out);
}

// Round 4
// 464.363 us; speedup vs baseline: 8.6423x; 1.1508x over previous
//
#include <hip/hip_runtime.h>

#define BS   16
#define NMEM 256
#define NQ   63
#define T    64          // NQ + 1
#define D    512
#define H    512
#define G4   2048        // 4*H

#define K2C  2.885390081777927f   // 2*log2(e)

typedef __attribute__((ext_vector_type(8))) short short8;
typedef __attribute__((ext_vector_type(4))) float float4v;

// ---------------- workspace layout (float offsets) ----------------
enum : size_t {
    OFF_XW  = 0,                            // [T][BS][G4]
    OFF_YS  = OFF_XW  + (size_t)T*BS*G4,    // [T+1][BS][H]  (fp32, b-major, for q-gemm)
    OFF_HB  = OFF_YS  + (size_t)(T+1)*BS*H, // [T+1][2][8192] bf16 hi/lo
    OFF_AF  = OFF_HB  + (size_t)(T+1)*BS*H, // [BS][NMEM][H]
    OFF_Q   = OFF_AF  + (size_t)BS*NMEM*H,  // [T][BS][H]
    OFF_X   = OFF_Q   + (size_t)T*BS*H,     // [T][BS][D]
    OFF_B   = OFF_X   + (size_t)T*BS*D,     // [G4]
    OFF_BAR = OFF_B   + (size_t)G4,         // 512 ints: 32 flags, stride 16
};

__device__ inline unsigned short bf16_rn(float x) {
    union { float f; unsigned u; } a; a.f = x;
    unsigned r = a.u + 0x7FFFu + ((a.u >> 16) & 1u);
    return (unsigned short)(r >> 16);
}
__device__ inline float bf16_to_f(unsigned short s) {
    union { float f; unsigned u; } a; a.u = ((unsigned)s) << 16;
    return a.f;
}

// ---------------- prep: build x, bias, hbuf[0] ----------------
__global__ void prep(const float* __restrict__ lstm_in, const float* __restrict__ init_h,
                     const float* __restrict__ init_i,
                     const float* __restrict__ b_ih, const float* __restrict__ b_hh,
                     float* __restrict__ xbuf, float* __restrict__ biasbuf,
                     unsigned short* __restrict__ hb0)
{
    int i = blockIdx.x * blockDim.x + threadIdx.x;
    const int NX = T*BS*D;
    if (i < NX) {
        int d = i & 511; int r = i >> 9; int t = r >> 4; int b = r & 15;
        float v = (t == 0) ? init_i[d] : lstm_in[((size_t)(b*NQ) + (t-1))*D + d];
        __builtin_nontemporal_store(v, xbuf + i);
    } else if (i < NX + G4) {
        int j = i - NX; biasbuf[j] = b_ih[j] + b_hh[j];
    } else if (i < NX + G4 + 8192) {
        int e = i - (NX + G4);
        int iw = e & 7;
        int k = ((e >> 3) >> 4) * 8 + iw;
        float h0 = init_h[k];
        unsigned short hi = bf16_rn(h0);
        unsigned short lo = bf16_rn(h0 - bf16_to_f(hi));
        hb0[e] = hi;
        hb0[8192 + e] = lo;
    }
}

// ---------------- split-bf16 MFMA GEMM unit ----------------
// 256 threads compute a 64x64 C tile of A[M,K] @ op(B), fp32 in/out.
// BT=true: B is [N,K] (C = A*B^T). BT=false: B is [K,N].
// C = Ah*Bh + Al*Bh + Ah*Bl (split-bf16, ~2^-16 relative).
template<bool BT>
__device__ inline void gemm_unit(const float* __restrict__ A, const float* __restrict__ B,
                                 float* __restrict__ C, const float* __restrict__ bias,
                                 int N, int K, int tm, int tn, int t2)
{
    const int w = t2 >> 6, lane = t2 & 63;
    const int quad = lane >> 4, l15 = lane & 15;
    const int am = tm + w*16 + l15;
    float4v acch[4] = {{0,0,0,0},{0,0,0,0},{0,0,0,0},{0,0,0,0}};
    float4v accl[4] = {{0,0,0,0},{0,0,0,0},{0,0,0,0},{0,0,0,0}};
    for (int k0 = 0; k0 < K; k0 += 32) {
        const float* ap = A + (size_t)am*K + k0 + quad*8;
        float4 a0 = *(const float4*)ap, a1 = *(const float4*)(ap+4);
        float av[8] = {a0.x,a0.y,a0.z,a0.w,a1.x,a1.y,a1.z,a1.w};
        short8 ah, al;
#pragma unroll
        for (int i = 0; i < 8; ++i) {
            unsigned short hi = bf16_rn(av[i]);
            ah[i] = (short)hi; al[i] = (short)bf16_rn(av[i] - bf16_to_f(hi));
        }
#pragma unroll
        for (int ni = 0; ni < 4; ++ni) {
            const int n = tn + ni*16 + l15;
            float bv[8];
            if (BT) {
                const float* bp = B + (size_t)n*K + k0 + quad*8;
                float4 b0 = *(const float4*)bp, b1 = *(const float4*)(bp+4);
                bv[0]=b0.x; bv[1]=b0.y; bv[2]=b0.z; bv[3]=b0.w;
                bv[4]=b1.x; bv[5]=b1.y; bv[6]=b1.z; bv[7]=b1.w;
            } else {
                const float* bp = B + (size_t)(k0 + quad*8)*N + n;
#pragma unroll
                for (int i = 0; i < 8; ++i) bv[i] = bp[(size_t)i*N];
            }
            short8 bh, bl;
#pragma unroll
            for (int i = 0; i < 8; ++i) {
                unsigned short hi = bf16_rn(bv[i]);
                bh[i] = (short)hi; bl[i] = (short)bf16_rn(bv[i] - bf16_to_f(hi));
            }
            acch[ni] = __builtin_amdgcn_mfma_f32_16x16x32_bf16(ah, bh, acch[ni], 0, 0, 0);
            accl[ni] = __builtin_amdgcn_mfma_f32_16x16x32_bf16(al, bh, accl[ni], 0, 0, 0);
            accl[ni] = __builtin_amdgcn_mfma_f32_16x16x32_bf16(ah, bl, accl[ni], 0, 0, 0);
        }
    }
#pragma unroll
    for (int ni = 0; ni < 4; ++ni) {
        const int n = tn + ni*16 + l15;
        float bb = bias ? bias[n] : 0.f;
        float4v r = acch[ni] + accl[ni];
#pragma unroll
        for (int j = 0; j < 4; ++j) {
            int row = tm + w*16 + quad*4 + j;
            __builtin_nontemporal_store(r[j] + bb, C + (size_t)row*N + n);
        }
    }
}

template<bool BT>
__global__ __launch_bounds__(256) void gemm_mfma(const float* __restrict__ A,
                                                 const float* __restrict__ B,
                                                 float* __restrict__ C,
                                                 const float* __restrict__ bias,
                                                 int N, int K)
{
    gemm_unit<BT>(A, B, C, bias, N, K, blockIdx.y*64, blockIdx.x*64, threadIdx.x);
}

// ---------------- persistent LSTM (blocks 0-31) + fused af GEMM (blocks 32-287) ----
// lstm: block jt owns hidden j-tile of 16 x 4 gates; 8 waves = (gate, k-half);
// weights as bf16 hi/lo B-fragments in VGPRs; h exchanged via L3 (bf16 hi/lo);
// barrier v4: per-block release flags + wave-parallel poll + one acquire fence.
// af: blocks 32-287 each run two independent 64x64 gemm_unit tiles of ks@wm.
__global__ __launch_bounds__(512, 2) void lstm_af(
    const float* __restrict__ xW,        // [T][BS][G4]
    const float* __restrict__ w_hh,      // [G4][H]
    const float* __restrict__ init_c,    // [H]
    const float* __restrict__ ks,        // [BS*NMEM][D]
    const float* __restrict__ wm,        // [D][H]
    float* __restrict__ ys,              // [T+1][BS][H]
    unsigned short* __restrict__ hbuf,   // [T+1][2][8192]
    float* __restrict__ af,              // [BS*NMEM][H]
    int* __restrict__ flags)             // 32 flags, stride 16 ints
{
    const int tid = threadIdx.x;

    if (blockIdx.x >= 32) {
        // ---------- fused af = ks @ wm (split-bf16 MFMA, no LDS, no barriers) ------
        const int u = tid >> 8;                    // two 256-thr units per block
        const int tau = (blockIdx.x - 32)*2 + u;   // 0..511 tiles: M=4096/64 x N=512/64
        gemm_unit<false>(ks, wm, af, nullptr, H, D, (tau >> 3)*64, (tau & 7)*64, tid & 255);
        return;
    }

    // ---------- LSTM recurrence ----------
    __shared__ float smem[3328];
    float* part = smem;              // [8][64][4]
    float* cst  = smem + 2048;       // [16][16]
    float* xwb  = smem + 2304;       // [4][16][16]  (gate, b, j16) staged xW[t]

    const int jt    = blockIdx.x;
    const int w     = tid >> 6;
    const int g     = w >> 1;
    const int khalf = w & 1;
    const int lane  = tid & 63;
    const int quad  = lane >> 4;
    const int l15   = lane & 15;

    // one-time weight preload -> bf16 hi/lo B-fragments in VGPRs
    short8 bh[8], bl[8];
    {
        const int row = g*512 + jt*16 + l15;
        const float* wr = w_hh + (size_t)row*H + khalf*256 + quad*8;
#pragma unroll
        for (int kt = 0; kt < 8; ++kt) {
            const float* wp = wr + kt*32;
#pragma unroll
            for (int i = 0; i < 8; ++i) {
                float v = wp[i];
                unsigned short hi = bf16_rn(v);
                bh[kt][i] = (short)hi;
                bl[kt][i] = (short)bf16_rn(v - bf16_to_f(hi));
            }
        }
    }

    const int b2 = tid >> 4, j16 = tid & 15;       // finalize mapping (tid<256)
    if (tid < 256) cst[b2*16 + j16] = init_c[jt*16 + j16];
    if (tid >= 256) {                              // stage xW[0] -> LDS
        int ti = tid - 256;
        int bb = ti >> 4, s = ti & 15;
        int gg = s & 3, j4 = (s >> 2) << 2;
        float4 v = *(const float4*)(xW + (size_t)bb*G4 + gg*512 + jt*16 + j4);
        float* dst = xwb + gg*256 + bb*16 + j4;
        dst[0]=v.x; dst[1]=v.y; dst[2]=v.z; dst[3]=v.w;
    }
    __syncthreads();

    for (int t = 0; t < T; ++t) {
        // ---- load h_t A-fragments ----
        const short8* hhi = (const short8*)(hbuf + (size_t)t*16384);
        const short8* hlo = hhi + 1024;
        short8 ah[8], al[8];
#pragma unroll
        for (int kt = 0; kt < 8; ++kt) {
            int c = ((khalf*8 + kt)*4 + quad)*16 + l15;
            ah[kt] = hhi[c];
            al[kt] = hlo[c];
        }
        // ---- split-bf16 MFMA ----
        float4v a0 = {0.f,0.f,0.f,0.f}, a1 = {0.f,0.f,0.f,0.f};
#pragma unroll
        for (int kt = 0; kt < 8; ++kt) {
            a0 = __builtin_amdgcn_mfma_f32_16x16x32_bf16(ah[kt], bh[kt], a0, 0, 0, 0);
            a1 = __builtin_amdgcn_mfma_f32_16x16x32_bf16(al[kt], bh[kt], a1, 0, 0, 0);
            a1 = __builtin_amdgcn_mfma_f32_16x16x32_bf16(ah[kt], bl[kt], a1, 0, 0, 0);
        }
        a0 += a1;
        *(float4v*)&part[(w*64 + lane)*4] = a0;    // D: m(b)=quad*4+reg, n(j)=lane&15
        __syncthreads();

        // ---- finalize: 256 threads = (b2, j16) ----
        if (tid < 256) {
            const int lsrc = ((b2 >> 2)*16 + j16)*4, r = b2 & 3;
            float gi = part[(0*256) + lsrc + r] + part[(1*256) + lsrc + r] + xwb[0*256 + b2*16 + j16];
            float gf = part[(2*256) + lsrc + r] + part[(3*256) + lsrc + r] + xwb[1*256 + b2*16 + j16];
            float gg = part[(4*256) + lsrc + r] + part[(5*256) + lsrc + r] + xwb[2*256 + b2*16 + j16];
            float go = part[(6*256) + lsrc + r] + part[(7*256) + lsrc + r] + xwb[3*256 + b2*16 + j16];
            float si = 1.f/(1.f+__expf(-gi));
            float sf = 1.f/(1.f+__expf(-gf));
            float so = 1.f/(1.f+__expf(-go));
            float cn = sf*cst[b2*16 + j16] + si*tanhf(gg);
            float hn = so*tanhf(cn);
            cst[b2*16 + j16] = cn;
            __builtin_nontemporal_store(hn, ys + (size_t)(t+1)*BS*H + b2*H + jt*16 + j16);
            const int k = jt*16 + j16;
            const int e = ((k >> 3)*16 + b2)*8 + (k & 7);
            unsigned short hi = bf16_rn(hn);
            unsigned short* hb1 = hbuf + (size_t)(t+1)*16384;
            hb1[e]        = hi;                       // plain; published by wbl2 in release
            hb1[8192 + e] = bf16_rn(hn - bf16_to_f(hi));
        }
        __syncthreads();   // per-wave vmcnt drain before barrier -> stores in L2

        if (t < T-1) {
            // arrival FIRST so its vmcnt(0) is clean (prefetch loads come after)
            if (tid == 0)
                __hip_atomic_store(&flags[jt*16], t+1, __ATOMIC_RELEASE, __HIP_MEMORY_SCOPE_AGENT);
            if (tid >= 256) {                       // stage xW[t+1] under the wait
                int ti = tid - 256;
                int bb = ti >> 4, s = ti & 15;
                int gg2 = s & 3, j4 = (s >> 2) << 2;
                float4 v = *(const float4*)(xW + (size_t)(t+1)*BS*G4 + bb*G4 + gg2*512 + jt*16 + j4);
                float* dst = xwb + gg2*256 + bb*16 + j4;
                dst[0]=v.x; dst[1]=v.y; dst[2]=v.z; dst[3]=v.w;
            }
            if (tid < 64) {                         // wave-parallel poll of 32 flags
                const int fidx = (tid & 31) << 4;
                int v;
                do {
                    v = __hip_atomic_load(&flags[fidx], __ATOMIC_RELAXED, __HIP_MEMORY_SCOPE_AGENT);
                } while (!__all(v >= t+1));
                __builtin_amdgcn_fence(__ATOMIC_ACQUIRE, "agent");  // one L1+L2 inv
            }
            __syncthreads();
        }
    }
}

// ---------------- fused attention: score[b,t,m] = sum_h tanh(af+q)*v ----------------
__global__ __launch_bounds__(256) void attn(const float* __restrict__ af,
                                            const float* __restrict__ q,
                                            const float* __restrict__ v,
                                            float* __restrict__ out)
{
    __shared__ float afs[64][68];
    __shared__ float qs[4][516];
    __shared__ float vs[512];
    const int tid = threadIdx.x;
    const int mc = blockIdx.x, tc = blockIdx.y, b = blockIdx.z;
    for (int i = tid; i < 4*128; i += 256) {
        int t = i >> 7, h4 = (i & 127) << 2;
        float4 x = *(const float4*)(q + ((size_t)((tc*4 + t)*16 + b) << 9) + h4);
        x.x *= K2C; x.y *= K2C; x.z *= K2C; x.w *= K2C;
        *(float4*)&qs[t][h4] = x;
    }
    for (int i = tid; i < 128; i += 256)
        *(float4*)&vs[i << 2] = *(const float4*)(v + (i << 2));
    const int ml = tid & 63, tg = tid >> 6;
    float acc = 0.f;
    for (int hc = 0; hc < 8; ++hc) {
        __syncthreads();
        for (int i = tid; i < 64*16; i += 256) {
            int m = i >> 4, h4 = (i & 15) << 2;
            float4 x = *(const float4*)(af + ((size_t)(b*NMEM + mc*64 + m) << 9) + hc*64 + h4);
            x.x *= K2C; x.y *= K2C; x.z *= K2C; x.w *= K2C;
            *(float4*)&afs[m][h4] = x;
        }
        __syncthreads();
#pragma unroll
        for (int h8 = 0; h8 < 8; ++h8) {
            float4 a0 = *(const float4*)&afs[ml][h8*8 + 0];
            float4 a1 = *(const float4*)&afs[ml][h8*8 + 4];
            float4 v0 = *(const float4*)&vs[hc*64 + h8*8 + 0];
            float4 v1 = *(const float4*)&vs[hc*64 + h8*8 + 4];
            float4 q0 = *(const float4*)&qs[tg][hc*64 + h8*8 + 0];
            float4 q1 = *(const float4*)&qs[tg][hc*64 + h8*8 + 4];
            const float* ap0 = (const float*)&a0; const float* ap1 = (const float*)&a1;
            const float* vp0 = (const float*)&v0; const float* vp1 = (const float*)&v1;
            const float* qp0 = (const float*)&q0; const float* qp1 = (const float*)&q1;
            float s = acc;
#pragma unroll
            for (int j = 0; j < 4; ++j) {
                float e = exp2f(ap0[j] + qp0[j]);
                s = fmaf(vp0[j], __builtin_amdgcn_rcpf(e + 1.f), s);
            }
#pragma unroll
            for (int j = 0; j < 4; ++j) {
                float e = exp2f(ap1[j] + qp1[j]);
                s = fmaf(vp1[j], __builtin_amdgcn_rcpf(e + 1.f), s);
            }
            acc = s;
        }
    }
    float Sv = 0.f;
    for (int i = 0; i < 512; i += 4) {
        float4 t4 = *(const float4*)&vs[i];
        Sv += t4.x + t4.y + t4.z + t4.w;
    }
    out[((size_t)b*T + tc*4 + tg)*NMEM + mc*64 + ml] = Sv - 2.f*acc;
}

extern "C" void kernel_launch(void* const* d_in, const int* in_sizes, int n_in,
                              void* d_out, int out_size, void* d_ws, size_t ws_size,
                              hipStream_t stream)
{
    const float* ks      = (const float*)d_in[0];
    const float* lstm_in = (const float*)d_in[2];
    const float* init_h  = (const float*)d_in[3];
    const float* init_c  = (const float*)d_in[4];
    const float* init_i  = (const float*)d_in[5];
    const float* w_ih    = (const float*)d_in[6];
    const float* w_hh    = (const float*)d_in[7];
    const float* b_ih    = (const float*)d_in[8];
    const float* b_hh    = (const float*)d_in[9];
    const float* wm      = (const float*)d_in[10];
    const float* wq      = (const float*)d_in[11];
    const float* av      = (const float*)d_in[12];

    float* ws   = (float*)d_ws;
    float* xW   = ws + OFF_XW;
    float* ys   = ws + OFF_YS;
    unsigned short* hbuf = (unsigned short*)(ws + OFF_HB);
    float* af   = ws + OFF_AF;
    float* qb   = ws + OFF_Q;
    float* xb   = ws + OFF_X;
    float* bias = ws + OFF_B;
    int*   flags= (int*)(ws + OFF_BAR);

    hipMemsetAsync(flags, 0, 512*sizeof(int), stream);

    const int prep_n = T*BS*D + G4 + 8192;
    prep<<<(prep_n + 255)/256, 256, 0, stream>>>(lstm_in, init_h, init_i,
                                                 b_ih, b_hh, xb, bias, hbuf);
    // xW[1024,2048] = x @ w_ih^T + bias   (split-bf16 MFMA)
    gemm_mfma<true><<<dim3(32, 16), 256, 0, stream>>>(xb, w_ih, xW, bias, G4, D);
    // LSTM recurrence (blocks 0-31) + af = ks @ wm (blocks 32-287)
    lstm_af<<<288, 512, 0, stream>>>(xW, w_hh, init_c, ks, wm, ys, hbuf, af, flags);
    // qb[1024,512] = ys[1..64] @ wq       (split-bf16 MFMA)
    gemm_mfma<false><<<dim3(8, 16), 256, 0, stream>>>(ys + BS*H, wq, qb, nullptr, H, H);
    attn<<<dim3(4, 16, 16), 256, 0, stream>>>(af, qb, av, (float*)d_out);
}